// Round 1
// baseline (253.072 us; speedup 1.0000x reference)
//
#include <hip/hip_runtime.h>
#include <math.h>

#define N_NODES 100000
#define D_INPUT 128
#define FDIM 128
#define A_HEADS 8
#define B_SEGS 512
#define D_OUTPUT 64
#define H_DIM 2304

// ---------------- segment boundaries (batch is sorted) ----------------
__global__ void seg_bounds_kernel(const int* __restrict__ batch, int n,
                                  int* __restrict__ seg_start) {
    int b = threadIdx.x;
    if (b > B_SEGS) return;
    int lo = 0, hi = n;
    while (lo < hi) {
        int mid = (lo + hi) >> 1;
        if (batch[mid] < b) lo = mid + 1; else hi = mid;
    }
    seg_start[b] = lo;  // first index with batch[i] >= b
}

// ---------------- xp = x @ W_in^T + b_in ----------------
// [N,128] = [N,128] x [128,128]^T.  64-node tiles, 4f x 8n micro-tile.
#define K1_BN 64
#define K1_KC 32
__global__ __launch_bounds__(256) void xp_kernel(const float* __restrict__ x,
        const float* __restrict__ W_in, const float* __restrict__ b_in,
        float* __restrict__ xp) {
    __shared__ float Wt[K1_KC][FDIM + 4];    // [kk][f]  (transposed)
    __shared__ float xT[K1_KC][K1_BN + 4];   // [kk][n]
    const int t = threadIdx.x;
    const int tf = t & 31;      // f0 = 4*tf
    const int tn = t >> 5;      // n0 = 8*tn
    const int n_base = blockIdx.x * K1_BN;
    float acc[4][8];
#pragma unroll
    for (int i = 0; i < 4; ++i)
#pragma unroll
        for (int j = 0; j < 8; ++j) acc[i][j] = 0.f;

    for (int kc = 0; kc < D_INPUT; kc += K1_KC) {
        {   // stage W (transpose): 32k x 128f
            const int kk = t & 31;
            const int f0 = t >> 5;   // 0..7
#pragma unroll
            for (int i = 0; i < 16; ++i) {
                int f = f0 + i * 8;
                Wt[kk][f] = W_in[f * D_INPUT + kc + kk];
            }
        }
        {   // stage x (transpose): 32k x 64n
            const int kk = t & 31;
            const int nn0 = t >> 5;
#pragma unroll
            for (int i = 0; i < 8; ++i) {
                int nn = nn0 + i * 8;
                int n = n_base + nn;
                xT[kk][nn] = (n < N_NODES) ? x[n * D_INPUT + kc + kk] : 0.f;
            }
        }
        __syncthreads();
#pragma unroll
        for (int kk = 0; kk < K1_KC; ++kk) {
            float4 wv = *(const float4*)&Wt[kk][tf * 4];
            float4 xa = *(const float4*)&xT[kk][tn * 8];
            float4 xb = *(const float4*)&xT[kk][tn * 8 + 4];
            float ws[4] = {wv.x, wv.y, wv.z, wv.w};
            float xs[8] = {xa.x, xa.y, xa.z, xa.w, xb.x, xb.y, xb.z, xb.w};
#pragma unroll
            for (int i = 0; i < 4; ++i)
#pragma unroll
                for (int j = 0; j < 8; ++j)
                    acc[i][j] = fmaf(ws[i], xs[j], acc[i][j]);
        }
        __syncthreads();
    }
    float4 bv = *(const float4*)&b_in[tf * 4];
    float bb[4] = {bv.x, bv.y, bv.z, bv.w};
#pragma unroll
    for (int j = 0; j < 8; ++j) {
        int n = n_base + tn * 8 + j;
        if (n < N_NODES) {
            float4 o4;
            o4.x = acc[0][j] + bb[0];
            o4.y = acc[1][j] + bb[1];
            o4.z = acc[2][j] + bb[2];
            o4.w = acc[3][j] + bb[3];
            *(float4*)&xp[n * FDIM + tf * 4] = o4;
        }
    }
}

// ---------------- score = exp(-|xp @ W_a^T + b_a|) ----------------
#define SC_NODES 32
__global__ __launch_bounds__(256) void score_kernel(const float* __restrict__ xp,
        const float* __restrict__ W_a, const float* __restrict__ b_a,
        float* __restrict__ score) {
    __shared__ float xs[SC_NODES][FDIM + 4];
    __shared__ float Was[A_HEADS][FDIM];
    const int t = threadIdx.x;
    const int n_base = blockIdx.x * SC_NODES;
    for (int idx = t; idx < A_HEADS * FDIM; idx += 256)
        Was[idx >> 7][idx & 127] = W_a[idx];
    for (int idx = t; idx < SC_NODES * FDIM; idx += 256) {
        int nn = idx >> 7, k = idx & 127;
        int n = n_base + nn;
        xs[nn][k] = (n < N_NODES) ? xp[n * FDIM + k] : 0.f;
    }
    __syncthreads();
    int nn = t >> 3, a = t & 7;
    int n = n_base + nn;
    if (n < N_NODES) {
        float s = 0.f;
#pragma unroll
        for (int c = 0; c < FDIM / 4; ++c) {
            float4 xv = *(const float4*)&xs[nn][c * 4];
            float4 wv = *(const float4*)&Was[a][c * 4];
            s = fmaf(xv.x, wv.x, s);
            s = fmaf(xv.y, wv.y, s);
            s = fmaf(xv.z, wv.z, s);
            s = fmaf(xv.w, wv.w, s);
        }
        score[n * A_HEADS + a] = __expf(-fabsf(s + b_a[a]));
    }
}

// ------- fused segment mean/max + projection through W_out agg columns -------
// one block per segment
__global__ __launch_bounds__(256) void seg_kernel(const float* __restrict__ xp,
        const float* __restrict__ score, const int* __restrict__ seg_start,
        const float* __restrict__ W_out, const float* __restrict__ b_out,
        float* __restrict__ agg_proj) {
    __shared__ float agg[A_HEADS * 2 * FDIM];   // [a][2F] : a*256 + j
    __shared__ float red_s[2][A_HEADS][FDIM];
    __shared__ float red_m[2][A_HEADS][FDIM];
    const int b = blockIdx.x;
    const int start = seg_start[b], end = seg_start[b + 1];
    const int count = end - start;
    const int t = threadIdx.x;
    const int g = t >> 7, f = t & 127;

    float sum[A_HEADS], mx[A_HEADS];
#pragma unroll
    for (int a = 0; a < A_HEADS; ++a) { sum[a] = 0.f; mx[a] = -INFINITY; }

    for (int n = start + g; n < end; n += 2) {
        float xv = xp[n * FDIM + f];
        float4 s0 = *(const float4*)&score[n * A_HEADS];
        float4 s1 = *(const float4*)&score[n * A_HEADS + 4];
        float ss[8] = {s0.x, s0.y, s0.z, s0.w, s1.x, s1.y, s1.z, s1.w};
#pragma unroll
        for (int a = 0; a < A_HEADS; ++a) {
            float e = ss[a] * xv;
            sum[a] += e;
            mx[a] = fmaxf(mx[a], e);
        }
    }
#pragma unroll
    for (int a = 0; a < A_HEADS; ++a) {
        red_s[g][a][f] = sum[a];
        red_m[g][a][f] = mx[a];
    }
    __syncthreads();
    if (t < 128) {
        float inv = 1.f / (float)max(count, 1);
#pragma unroll
        for (int a = 0; a < A_HEADS; ++a) {
            float sm = red_s[0][a][f] + red_s[1][a][f];
            float mv = fmaxf(red_m[0][a][f], red_m[1][a][f]);
            agg[a * 256 + f] = sm * inv;
            agg[a * 256 + 128 + f] = (count > 0) ? mv : 0.f;
        }
    }
    __syncthreads();
    // project: agg_proj[b][o] = sum_j agg[j] * W_out[o][256+j] + b_out[o]
    const int wave = t >> 6, lane = t & 63;
#pragma unroll
    for (int i = 0; i < 16; ++i) {
        int o = wave * 16 + i;
        const float* wrow = W_out + o * H_DIM + 256;
        float partial = 0.f;
#pragma unroll
        for (int c = 0; c < 8; ++c) {
            int j = c * 256 + lane * 4;
            float4 wv = *(const float4*)&wrow[j];
            float4 av = *(const float4*)&agg[j];
            partial = fmaf(wv.x, av.x, partial);
            partial = fmaf(wv.y, av.y, partial);
            partial = fmaf(wv.z, av.z, partial);
            partial = fmaf(wv.w, av.w, partial);
        }
#pragma unroll
        for (int m = 1; m < 64; m <<= 1)
            partial += __shfl_xor(partial, m);
        if (lane == 0) agg_proj[b * D_OUTPUT + o] = partial + b_out[o];
    }
}

// ---------------- out = relu([x|xp] @ Wc^T + agg_proj[batch]) ----------------
#define K4_BN 128
#define K4_KC 32
__global__ __launch_bounds__(256) void out_kernel(const float* __restrict__ x,
        const float* __restrict__ xp, const int* __restrict__ batch,
        const float* __restrict__ W_out, const float* __restrict__ agg_proj,
        float* __restrict__ out) {
    __shared__ float Wt[K4_KC][D_OUTPUT + 4];   // [kk][o]
    __shared__ float hT[K4_KC][K4_BN + 4];      // [kk][n]
    const int t = threadIdx.x;
    const int tf = t & 15;    // o0 = 4*tf
    const int tn = t >> 4;    // n0 = 8*tn  (0..15)
    const int n_base = blockIdx.x * K4_BN;
    float acc[4][8];
#pragma unroll
    for (int i = 0; i < 4; ++i)
#pragma unroll
        for (int j = 0; j < 8; ++j) acc[i][j] = 0.f;

    for (int kc = 0; kc < 2 * FDIM; kc += K4_KC) {
        const float* src = (kc < FDIM) ? x : xp;
        const int koff = kc & (FDIM - 1);
        {   // stage W columns kc..kc+31 for all 64 outputs
            int kk = t & 31, oo = t >> 5;  // oo 0..7
#pragma unroll
            for (int i = 0; i < 8; ++i) {
                int o = oo + i * 8;
                Wt[kk][o] = W_out[o * H_DIM + kc + kk];
            }
        }
        {   // stage h tile transposed: 32k x 128n
            int kk = t & 31, nn0 = t >> 5;
#pragma unroll
            for (int i = 0; i < 16; ++i) {
                int nn = nn0 + i * 8;
                int n = n_base + nn;
                hT[kk][nn] = (n < N_NODES) ? src[n * FDIM + koff + kk] : 0.f;
            }
        }
        __syncthreads();
#pragma unroll
        for (int kk = 0; kk < K4_KC; ++kk) {
            float4 wv = *(const float4*)&Wt[kk][tf * 4];
            float4 xa = *(const float4*)&hT[kk][tn * 8];
            float4 xb = *(const float4*)&hT[kk][tn * 8 + 4];
            float ws[4] = {wv.x, wv.y, wv.z, wv.w};
            float xs[8] = {xa.x, xa.y, xa.z, xa.w, xb.x, xb.y, xb.z, xb.w};
#pragma unroll
            for (int i = 0; i < 4; ++i)
#pragma unroll
                for (int j = 0; j < 8; ++j)
                    acc[i][j] = fmaf(ws[i], xs[j], acc[i][j]);
        }
        __syncthreads();
    }
#pragma unroll
    for (int j = 0; j < 8; ++j) {
        int n = n_base + tn * 8 + j;
        if (n < N_NODES) {
            int bseg = batch[n];
            float4 ap = *(const float4*)&agg_proj[bseg * D_OUTPUT + tf * 4];
            float4 o4;
            o4.x = fmaxf(acc[0][j] + ap.x, 0.f);
            o4.y = fmaxf(acc[1][j] + ap.y, 0.f);
            o4.z = fmaxf(acc[2][j] + ap.z, 0.f);
            o4.w = fmaxf(acc[3][j] + ap.w, 0.f);
            *(float4*)&out[n * D_OUTPUT + tf * 4] = o4;
        }
    }
}

extern "C" void kernel_launch(void* const* d_in, const int* in_sizes, int n_in,
                              void* d_out, int out_size, void* d_ws, size_t ws_size,
                              hipStream_t stream) {
    const float* x     = (const float*)d_in[0];
    const int*   batch = (const int*)d_in[1];
    // d_in[2] = num_segments scalar (compile-time 512)
    const float* W_in  = (const float*)d_in[3];
    const float* b_in  = (const float*)d_in[4];
    const float* W_a   = (const float*)d_in[5];
    const float* b_a   = (const float*)d_in[6];
    const float* W_out = (const float*)d_in[7];
    const float* b_out = (const float*)d_in[8];
    float* out = (float*)d_out;

    float* ws = (float*)d_ws;
    float* xp       = ws;                          // N*128
    float* score    = xp + (size_t)N_NODES * FDIM; // N*8
    float* agg_proj = score + (size_t)N_NODES * A_HEADS; // 512*64
    int*   seg_start = (int*)(agg_proj + B_SEGS * D_OUTPUT); // 513 ints

    seg_bounds_kernel<<<1, 1024, 0, stream>>>(batch, N_NODES, seg_start);
    xp_kernel<<<(N_NODES + K1_BN - 1) / K1_BN, 256, 0, stream>>>(x, W_in, b_in, xp);
    score_kernel<<<(N_NODES + SC_NODES - 1) / SC_NODES, 256, 0, stream>>>(xp, W_a, b_a, score);
    seg_kernel<<<B_SEGS, 256, 0, stream>>>(xp, score, seg_start, W_out, b_out, agg_proj);
    out_kernel<<<(N_NODES + K4_BN - 1) / K4_BN, 256, 0, stream>>>(x, xp, batch, W_out, agg_proj, out);
}

// Round 2
// 137.334 us; speedup vs baseline: 1.8428x; 1.8428x over previous
//
#include <hip/hip_runtime.h>
#include <math.h>

#define N_NODES 100000
#define D_INPUT 128
#define FDIM 128
#define A_HEADS 8
#define B_SEGS 512
#define D_OUTPUT 64
#define H_DIM 2304

typedef __attribute__((ext_vector_type(8))) __bf16 bf16x8;
typedef __attribute__((ext_vector_type(4))) float f32x4;

static __device__ inline unsigned short f2bfu(float f) {
    unsigned u = __builtin_bit_cast(unsigned, f);
    u += 0x7fffu + ((u >> 16) & 1u);
    return (unsigned short)(u >> 16);
}
static __device__ inline unsigned packbf(float a, float b) {
    return (unsigned)f2bfu(a) | ((unsigned)f2bfu(b) << 16);
}
static __device__ inline float bfl(unsigned u) {
    unsigned x = u << 16; return __builtin_bit_cast(float, x);
}
static __device__ inline float bfh(unsigned u) {
    unsigned x = u & 0xffff0000u; return __builtin_bit_cast(float, x);
}

// ---------------- segment boundaries (batch is sorted) ----------------
__global__ void seg_bounds_kernel(const int* __restrict__ batch, int n,
                                  int* __restrict__ seg_start) {
    int b = threadIdx.x;
    if (b > B_SEGS) return;
    int lo = 0, hi = n;
    while (lo < hi) {
        int mid = (lo + hi) >> 1;
        if (batch[mid] < b) lo = mid + 1; else hi = mid;
    }
    seg_start[b] = lo;
}

// ---- fused: x->bf16, xp = x@W_in^T+b (MFMA), score = exp(-|xp@W_a^T+b_a|) ----
// 128-node tile, 256 threads (4 waves), each wave owns 32 nodes.
__global__ __launch_bounds__(256) void fused_in_kernel(
        const float* __restrict__ x, const float* __restrict__ W_in,
        const float* __restrict__ b_in, const float* __restrict__ W_a,
        const float* __restrict__ b_a, unsigned* __restrict__ xb,
        unsigned* __restrict__ xpb, float* __restrict__ score) {
    __shared__ __align__(16) unsigned XbU[128 * 68];  // x tile bf16, later XP tile
    __shared__ __align__(16) unsigned WbU[128 * 68];  // W_in bf16 [f][k]
    __shared__ __align__(16) unsigned WaU[16 * 68];   // W_a bf16, rows 8..15 zero
    const int t = threadIdx.x;
    const int n_base = blockIdx.x * 128;

    // stage W_in -> bf16 LDS
#pragma unroll
    for (int i = 0; i < 32; ++i) {
        int idx = i * 256 + t, row = idx >> 6, cu = idx & 63;
        float2 wv = *(const float2*)(W_in + row * 128 + cu * 2);
        WbU[row * 68 + cu] = packbf(wv.x, wv.y);
    }
    // stage x -> bf16 LDS + write xb global
#pragma unroll
    for (int i = 0; i < 32; ++i) {
        int idx = i * 256 + t, row = idx >> 6, cu = idx & 63;
        int n = n_base + row;
        float2 xv = make_float2(0.f, 0.f);
        if (n < N_NODES) xv = *(const float2*)(x + (size_t)n * 128 + cu * 2);
        unsigned u = packbf(xv.x, xv.y);
        XbU[row * 68 + cu] = u;
        if (n < N_NODES) xb[(size_t)n * 64 + cu] = u;
    }
    // W_a: zero pad rows 8..15, fill rows 0..7 (disjoint locations, no barrier)
    {
        int r0 = 8 + (t >> 6), cu = t & 63;
        WaU[r0 * 68 + cu] = 0u;
        WaU[(r0 + 4) * 68 + cu] = 0u;
        int row = t >> 6;
        float2 wv = *(const float2*)(W_a + row * 128 + cu * 2);
        WaU[row * 68 + cu] = packbf(wv.x, wv.y);
        wv = *(const float2*)(W_a + (row + 4) * 128 + cu * 2);
        WaU[(row + 4) * 68 + cu] = packbf(wv.x, wv.y);
    }
    __syncthreads();

    const int w = t >> 6, l = t & 63, lr = l & 15, lk = l >> 4;
    f32x4 acc[2][8];
    const f32x4 z4 = {0.f, 0.f, 0.f, 0.f};
#pragma unroll
    for (int m = 0; m < 2; ++m)
#pragma unroll
        for (int nr = 0; nr < 8; ++nr) acc[m][nr] = z4;

#pragma unroll
    for (int ks = 0; ks < 4; ++ks) {
        bf16x8 a0 = *(const bf16x8*)&XbU[(w * 32 + lr) * 68 + ks * 16 + lk * 4];
        bf16x8 a1 = *(const bf16x8*)&XbU[(w * 32 + 16 + lr) * 68 + ks * 16 + lk * 4];
#pragma unroll
        for (int nr = 0; nr < 8; ++nr) {
            bf16x8 b = *(const bf16x8*)&WbU[(nr * 16 + lr) * 68 + ks * 16 + lk * 4];
            acc[0][nr] = __builtin_amdgcn_mfma_f32_16x16x32_bf16(a0, b, acc[0][nr], 0, 0, 0);
            acc[1][nr] = __builtin_amdgcn_mfma_f32_16x16x32_bf16(a1, b, acc[1][nr], 0, 0, 0);
        }
    }
    // bias b_in (col = nr*16+lr)
#pragma unroll
    for (int nr = 0; nr < 8; ++nr) {
        float bf = b_in[nr * 16 + lr];
#pragma unroll
        for (int m = 0; m < 2; ++m) {
            acc[m][nr].x += bf; acc[m][nr].y += bf;
            acc[m][nr].z += bf; acc[m][nr].w += bf;
        }
    }
    __syncthreads();   // everyone done reading Xb/Wb
    // write XP (bf16) over the Xb LDS region
    unsigned short* XPs = (unsigned short*)XbU;
#pragma unroll
    for (int m = 0; m < 2; ++m)
#pragma unroll
        for (int nr = 0; nr < 8; ++nr)
#pragma unroll
            for (int r = 0; r < 4; ++r) {
                int row = w * 32 + m * 16 + lk * 4 + r;
                int col = nr * 16 + lr;
                XPs[row * 136 + col] = f2bfu(((const float*)&acc[m][nr])[r]);
            }
    __syncthreads();

    // score = exp(-|XP @ Wa^T + b_a|) via one MFMA column-block (cols 8..15 padded)
    f32x4 sa[2] = {z4, z4};
#pragma unroll
    for (int ks = 0; ks < 4; ++ks) {
        bf16x8 a0 = *(const bf16x8*)&XbU[(w * 32 + lr) * 68 + ks * 16 + lk * 4];
        bf16x8 a1 = *(const bf16x8*)&XbU[(w * 32 + 16 + lr) * 68 + ks * 16 + lk * 4];
        bf16x8 b = *(const bf16x8*)&WaU[lr * 68 + ks * 16 + lk * 4];
        sa[0] = __builtin_amdgcn_mfma_f32_16x16x32_bf16(a0, b, sa[0], 0, 0, 0);
        sa[1] = __builtin_amdgcn_mfma_f32_16x16x32_bf16(a1, b, sa[1], 0, 0, 0);
    }
    if (lr < A_HEADS) {
        float ba = b_a[lr];
#pragma unroll
        for (int m = 0; m < 2; ++m)
#pragma unroll
            for (int r = 0; r < 4; ++r) {
                int n = n_base + w * 32 + m * 16 + lk * 4 + r;
                if (n < N_NODES)
                    score[(size_t)n * 8 + lr] =
                        __expf(-fabsf(((const float*)&sa[m])[r] + ba));
            }
    }
    // write xpb global (coalesced) from XP LDS
#pragma unroll
    for (int i = 0; i < 32; ++i) {
        int idx = i * 256 + t, row = idx >> 6, cu = idx & 63;
        int n = n_base + row;
        if (n < N_NODES) xpb[(size_t)n * 64 + cu] = XbU[row * 68 + cu];
    }
}

// ------- fused segment mean/max + projection through W_out agg columns -------
__global__ __launch_bounds__(256) void seg_kernel(
        const unsigned* __restrict__ xpb, const float* __restrict__ score,
        const int* __restrict__ seg_start, const float* __restrict__ W_out,
        const float* __restrict__ b_out, float* __restrict__ agg_proj) {
    __shared__ float red_s[4][8][128];
    __shared__ float red_m[4][8][128];
    __shared__ float agg[8 * 256];
    const int b = blockIdx.x;
    const int start = seg_start[b], end = seg_start[b + 1];
    const int count = end - start;
    const int t = threadIdx.x;
    const int j = t & 63, g = t >> 6;

    float sum0[8], sum1[8], mx0[8], mx1[8];
#pragma unroll
    for (int a = 0; a < 8; ++a) {
        sum0[a] = 0.f; sum1[a] = 0.f; mx0[a] = -INFINITY; mx1[a] = -INFINITY;
    }
    for (int n = start + g; n < end; n += 4) {
        unsigned u = xpb[(size_t)n * 64 + j];
        float f0 = bfl(u), f1 = bfh(u);
        const float4* sp = (const float4*)(score + (size_t)n * 8);
        float4 s0 = sp[0], s1 = sp[1];
        float ss[8] = {s0.x, s0.y, s0.z, s0.w, s1.x, s1.y, s1.z, s1.w};
#pragma unroll
        for (int a = 0; a < 8; ++a) {
            float e0 = ss[a] * f0, e1 = ss[a] * f1;
            sum0[a] += e0; sum1[a] += e1;
            mx0[a] = fmaxf(mx0[a], e0); mx1[a] = fmaxf(mx1[a], e1);
        }
    }
#pragma unroll
    for (int a = 0; a < 8; ++a) {
        red_s[g][a][2 * j] = sum0[a]; red_s[g][a][2 * j + 1] = sum1[a];
        red_m[g][a][2 * j] = mx0[a];  red_m[g][a][2 * j + 1] = mx1[a];
    }
    __syncthreads();
    float inv = 1.f / (float)max(count, 1);
#pragma unroll
    for (int rep = 0; rep < 4; ++rep) {
        int idx = rep * 256 + t, a = idx >> 7, f = idx & 127;
        float sm = red_s[0][a][f] + red_s[1][a][f] + red_s[2][a][f] + red_s[3][a][f];
        float mv = fmaxf(fmaxf(red_m[0][a][f], red_m[1][a][f]),
                         fmaxf(red_m[2][a][f], red_m[3][a][f]));
        agg[a * 256 + f] = sm * inv;
        agg[a * 256 + 128 + f] = (count > 0) ? mv : 0.f;
    }
    __syncthreads();
    const int wave = t >> 6, lane = t & 63;
#pragma unroll
    for (int i = 0; i < 16; ++i) {
        int o = wave * 16 + i;
        const float* wrow = W_out + (size_t)o * H_DIM + 256;
        float partial = 0.f;
#pragma unroll
        for (int c = 0; c < 8; ++c) {
            int jj = c * 256 + lane * 4;
            float4 wv = *(const float4*)&wrow[jj];
            float4 av = *(const float4*)&agg[jj];
            partial = fmaf(wv.x, av.x, partial);
            partial = fmaf(wv.y, av.y, partial);
            partial = fmaf(wv.z, av.z, partial);
            partial = fmaf(wv.w, av.w, partial);
        }
#pragma unroll
        for (int m = 1; m < 64; m <<= 1) partial += __shfl_xor(partial, m);
        if (lane == 0) agg_proj[b * D_OUTPUT + o] = partial + b_out[o];
    }
}

// -------- out = relu([xb|xpb] @ W_out[:, :256]^T + agg_proj[batch]) ----------
// 256-node tile, 4 waves x 64 nodes; A fragments straight from global bf16.
__global__ __launch_bounds__(256) void out_kernel(
        const unsigned* __restrict__ xb, const unsigned* __restrict__ xpb,
        const int* __restrict__ batch, const float* __restrict__ W_out,
        const float* __restrict__ agg_proj, float* __restrict__ out) {
    __shared__ __align__(16) unsigned WoU[64 * 132];  // W_out[:, :256] bf16
    const int t = threadIdx.x;
#pragma unroll
    for (int i = 0; i < 32; ++i) {
        int idx = i * 256 + t, row = idx >> 7, cu = idx & 127;
        float2 wv = *(const float2*)(W_out + (size_t)row * H_DIM + cu * 2);
        WoU[row * 132 + cu] = packbf(wv.x, wv.y);
    }
    __syncthreads();
    const int w = t >> 6, l = t & 63, lr = l & 15, lk = l >> 4;
    const int nb = blockIdx.x * 256 + w * 64;
    f32x4 acc[4][4];
    const f32x4 z4 = {0.f, 0.f, 0.f, 0.f};
#pragma unroll
    for (int m = 0; m < 4; ++m)
#pragma unroll
        for (int nr = 0; nr < 4; ++nr) acc[m][nr] = z4;

#pragma unroll 2
    for (int ks = 0; ks < 8; ++ks) {
        const unsigned* src = (ks < 4) ? xb : xpb;
        int koff = (ks & 3) * 16 + lk * 4;
        bf16x8 af[4];
#pragma unroll
        for (int m = 0; m < 4; ++m) {
            int n = nb + m * 16 + lr;
            if (n > N_NODES - 1) n = N_NODES - 1;
            af[m] = *(const bf16x8*)&src[(size_t)n * 64 + koff];
        }
#pragma unroll
        for (int nr = 0; nr < 4; ++nr) {
            bf16x8 bfr = *(const bf16x8*)&WoU[(nr * 16 + lr) * 132 + ks * 16 + lk * 4];
#pragma unroll
            for (int m = 0; m < 4; ++m)
                acc[m][nr] = __builtin_amdgcn_mfma_f32_16x16x32_bf16(af[m], bfr, acc[m][nr], 0, 0, 0);
        }
    }
#pragma unroll
    for (int m = 0; m < 4; ++m)
#pragma unroll
        for (int r = 0; r < 4; ++r) {
            int n = nb + m * 16 + lk * 4 + r;
            if (n < N_NODES) {
                int bs = batch[n];
                const float* ap = agg_proj + (size_t)bs * 64;
#pragma unroll
                for (int nr = 0; nr < 4; ++nr) {
                    int f = nr * 16 + lr;
                    out[(size_t)n * 64 + f] =
                        fmaxf(((const float*)&acc[m][nr])[r] + ap[f], 0.f);
                }
            }
        }
}

extern "C" void kernel_launch(void* const* d_in, const int* in_sizes, int n_in,
                              void* d_out, int out_size, void* d_ws, size_t ws_size,
                              hipStream_t stream) {
    const float* x     = (const float*)d_in[0];
    const int*   batch = (const int*)d_in[1];
    const float* W_in  = (const float*)d_in[3];
    const float* b_in  = (const float*)d_in[4];
    const float* W_a   = (const float*)d_in[5];
    const float* b_a   = (const float*)d_in[6];
    const float* W_out = (const float*)d_in[7];
    const float* b_out = (const float*)d_in[8];
    float* out = (float*)d_out;

    unsigned* xb  = (unsigned*)d_ws;                       // N*64 u32 (bf16 x)
    unsigned* xpb = xb + (size_t)N_NODES * 64;             // N*64 u32 (bf16 xp)
    float* score  = (float*)(xpb + (size_t)N_NODES * 64);  // N*8 f32
    float* agg_proj = score + (size_t)N_NODES * 8;         // 512*64 f32
    int* seg_start = (int*)(agg_proj + B_SEGS * D_OUTPUT); // 513 ints

    seg_bounds_kernel<<<1, 1024, 0, stream>>>(batch, N_NODES, seg_start);
    fused_in_kernel<<<(N_NODES + 127) / 128, 256, 0, stream>>>(
        x, W_in, b_in, W_a, b_a, xb, xpb, score);
    seg_kernel<<<B_SEGS, 256, 0, stream>>>(xpb, score, seg_start, W_out, b_out, agg_proj);
    out_kernel<<<(N_NODES + 255) / 256, 256, 0, stream>>>(
        xb, xpb, batch, W_out, agg_proj, out);
}

// Round 3
// 130.240 us; speedup vs baseline: 1.9431x; 1.0545x over previous
//
#include <hip/hip_runtime.h>
#include <math.h>

#define N_NODES 100000
#define D_INPUT 128
#define FDIM 128
#define A_HEADS 8
#define B_SEGS 512
#define D_OUTPUT 64
#define H_DIM 2304

typedef __attribute__((ext_vector_type(8))) __bf16 bf16x8;
typedef __attribute__((ext_vector_type(4))) float f32x4;

static __device__ inline unsigned short f2bfu(float f) {
    unsigned u = __builtin_bit_cast(unsigned, f);
    u += 0x7fffu + ((u >> 16) & 1u);
    return (unsigned short)(u >> 16);
}
static __device__ inline unsigned packbf(float a, float b) {
    return (unsigned)f2bfu(a) | ((unsigned)f2bfu(b) << 16);
}
static __device__ inline float bfl(unsigned u) {
    unsigned x = u << 16; return __builtin_bit_cast(float, x);
}
static __device__ inline float bfh(unsigned u) {
    unsigned x = u & 0xffff0000u; return __builtin_bit_cast(float, x);
}
static __device__ inline bf16x8 pack8(float4 a, float4 b) {
    union { unsigned u[4]; bf16x8 v; } r;
    r.u[0] = packbf(a.x, a.y); r.u[1] = packbf(a.z, a.w);
    r.u[2] = packbf(b.x, b.y); r.u[3] = packbf(b.z, b.w);
    return r.v;
}

// ---------------- segment boundaries (batch is sorted) ----------------
__global__ void seg_bounds_kernel(const int* __restrict__ batch, int n,
                                  int* __restrict__ seg_start) {
    int b = threadIdx.x;
    if (b > B_SEGS) return;
    int lo = 0, hi = n;
    while (lo < hi) {
        int mid = (lo + hi) >> 1;
        if (batch[mid] < b) lo = mid + 1; else hi = mid;
    }
    seg_start[b] = lo;
}

// ------------- one-time weight conversion fp32 -> bf16 (packed u32) ---------
__global__ __launch_bounds__(256) void wconv_kernel(
        const float* __restrict__ W_in, const float* __restrict__ W_a,
        const float* __restrict__ W_out, unsigned* __restrict__ Wb,
        unsigned* __restrict__ Wa, unsigned* __restrict__ Wo) {
    const int t = threadIdx.x;
    for (int i = t; i < 128 * 64; i += 256) {            // W_in [128][128]
        float2 v = *(const float2*)(W_in + (size_t)i * 2);
        Wb[i] = packbf(v.x, v.y);
    }
    for (int i = t; i < 16 * 64; i += 256) {             // W_a padded to 16 rows
        if (i < 8 * 64) {
            float2 v = *(const float2*)(W_a + (size_t)i * 2);
            Wa[i] = packbf(v.x, v.y);
        } else Wa[i] = 0u;
    }
    for (int i = t; i < 64 * 128; i += 256) {            // W_out[:, :256]
        int row = i >> 7, cu = i & 127;
        float2 v = *(const float2*)(W_out + (size_t)row * H_DIM + cu * 2);
        Wo[i] = packbf(v.x, v.y);
    }
}

// ---- fused: xp = x@W_in^T+b (MFMA), score = exp(-|xp@W_a^T+b_a|) ----
// 64-node tile, 4 waves x 16 nodes. A from global fp32 (pack in regs),
// B (weights) from global bf16. Only XP tile in LDS (17KB).
__global__ __launch_bounds__(256) void fused_in_kernel(
        const float* __restrict__ x, const float* __restrict__ b_in,
        const float* __restrict__ b_a, const unsigned* __restrict__ Wb,
        const unsigned* __restrict__ Wa, unsigned* __restrict__ xpb,
        float* __restrict__ score) {
    __shared__ __align__(16) unsigned XP[64 * 68];
    unsigned short* XPs = (unsigned short*)XP;
    const int t = threadIdx.x;
    const int w = t >> 6, l = t & 63, lr = l & 15, lk = l >> 4;
    const int n_base = blockIdx.x * 64;
    const int arow = n_base + w * 16 + lr;
    const int arowc = min(arow, N_NODES - 1);

    const f32x4 z4 = {0.f, 0.f, 0.f, 0.f};
    f32x4 acc[8];
#pragma unroll
    for (int nr = 0; nr < 8; ++nr) acc[nr] = z4;

#pragma unroll
    for (int ks = 0; ks < 4; ++ks) {
        const float4* xp4 = (const float4*)(x + (size_t)arowc * 128 + ks * 32 + lk * 8);
        bf16x8 af = pack8(xp4[0], xp4[1]);
#pragma unroll
        for (int nr = 0; nr < 8; ++nr) {
            bf16x8 bfrag = *(const bf16x8*)&Wb[(nr * 16 + lr) * 64 + ks * 16 + lk * 4];
            acc[nr] = __builtin_amdgcn_mfma_f32_16x16x32_bf16(af, bfrag, acc[nr], 0, 0, 0);
        }
    }
    // bias + write XP tile (each wave writes only its own 16 rows)
#pragma unroll
    for (int nr = 0; nr < 8; ++nr) {
        float bf = b_in[nr * 16 + lr];
#pragma unroll
        for (int r = 0; r < 4; ++r) {
            int row = w * 16 + lk * 4 + r;
            XPs[row * 136 + nr * 16 + lr] = f2bfu(((const float*)&acc[nr])[r] + bf);
        }
    }
    // score MFMA: A = XP rows of this wave (same-wave LDS, no barrier needed)
    f32x4 sacc = z4;
#pragma unroll
    for (int ks = 0; ks < 4; ++ks) {
        bf16x8 af = *(const bf16x8*)&XPs[(w * 16 + lr) * 136 + ks * 32 + lk * 8];
        bf16x8 bfrag = *(const bf16x8*)&Wa[lr * 64 + ks * 16 + lk * 4];
        sacc = __builtin_amdgcn_mfma_f32_16x16x32_bf16(af, bfrag, sacc, 0, 0, 0);
    }
    if (lr < A_HEADS) {
        float ba = b_a[lr];
#pragma unroll
        for (int r = 0; r < 4; ++r) {
            int n = n_base + w * 16 + lk * 4 + r;
            if (n < N_NODES)
                score[(size_t)n * 8 + lr] =
                    __expf(-fabsf(((const float*)&sacc)[r] + ba));
        }
    }
    __syncthreads();
    // coalesced xpb store: 64 rows x 16 uint4
#pragma unroll
    for (int i = 0; i < 4; ++i) {
        int idx = i * 256 + t, row = idx >> 4, c4 = idx & 15;
        int n = n_base + row;
        if (n < N_NODES) {
            uint4 v = *(const uint4*)&XP[row * 68 + c4 * 4];
            *(uint4*)&xpb[(size_t)n * 64 + c4 * 4] = v;
        }
    }
}

// ------- fused segment mean/max + projection through W_out agg columns -------
__global__ __launch_bounds__(256) void seg_kernel(
        const unsigned* __restrict__ xpb, const float* __restrict__ score,
        const int* __restrict__ seg_start, const float* __restrict__ W_out,
        const float* __restrict__ b_out, float* __restrict__ agg_proj) {
    __shared__ float red_s[4][8][128];
    __shared__ float red_m[4][8][128];
    __shared__ float agg[8 * 256];
    const int b = blockIdx.x;
    const int start = seg_start[b], end = seg_start[b + 1];
    const int count = end - start;
    const int t = threadIdx.x;
    const int j = t & 63, g = t >> 6;

    float sum0[8], sum1[8], mx0[8], mx1[8];
#pragma unroll
    for (int a = 0; a < 8; ++a) {
        sum0[a] = 0.f; sum1[a] = 0.f; mx0[a] = -INFINITY; mx1[a] = -INFINITY;
    }
    for (int n = start + g; n < end; n += 4) {
        unsigned u = xpb[(size_t)n * 64 + j];
        float f0 = bfl(u), f1 = bfh(u);
        const float4* sp = (const float4*)(score + (size_t)n * 8);
        float4 s0 = sp[0], s1 = sp[1];
        float ss[8] = {s0.x, s0.y, s0.z, s0.w, s1.x, s1.y, s1.z, s1.w};
#pragma unroll
        for (int a = 0; a < 8; ++a) {
            float e0 = ss[a] * f0, e1 = ss[a] * f1;
            sum0[a] += e0; sum1[a] += e1;
            mx0[a] = fmaxf(mx0[a], e0); mx1[a] = fmaxf(mx1[a], e1);
        }
    }
#pragma unroll
    for (int a = 0; a < 8; ++a) {
        red_s[g][a][2 * j] = sum0[a]; red_s[g][a][2 * j + 1] = sum1[a];
        red_m[g][a][2 * j] = mx0[a];  red_m[g][a][2 * j + 1] = mx1[a];
    }
    __syncthreads();
    float inv = 1.f / (float)max(count, 1);
#pragma unroll
    for (int rep = 0; rep < 4; ++rep) {
        int idx = rep * 256 + t, a = idx >> 7, f = idx & 127;
        float sm = red_s[0][a][f] + red_s[1][a][f] + red_s[2][a][f] + red_s[3][a][f];
        float mv = fmaxf(fmaxf(red_m[0][a][f], red_m[1][a][f]),
                         fmaxf(red_m[2][a][f], red_m[3][a][f]));
        agg[a * 256 + f] = sm * inv;
        agg[a * 256 + 128 + f] = (count > 0) ? mv : 0.f;
    }
    __syncthreads();
    const int wave = t >> 6, lane = t & 63;
#pragma unroll
    for (int i = 0; i < 16; ++i) {
        int o = wave * 16 + i;
        const float* wrow = W_out + (size_t)o * H_DIM + 256;
        float partial = 0.f;
#pragma unroll
        for (int c = 0; c < 8; ++c) {
            int jj = c * 256 + lane * 4;
            float4 wv = *(const float4*)&wrow[jj];
            float4 av = *(const float4*)&agg[jj];
            partial = fmaf(wv.x, av.x, partial);
            partial = fmaf(wv.y, av.y, partial);
            partial = fmaf(wv.z, av.z, partial);
            partial = fmaf(wv.w, av.w, partial);
        }
#pragma unroll
        for (int m = 1; m < 64; m <<= 1) partial += __shfl_xor(partial, m);
        if (lane == 0) agg_proj[b * D_OUTPUT + o] = partial + b_out[o];
    }
}

// -------- out = relu([x|xp] @ W_out[:, :256]^T + agg_proj[batch]) ----------
// 128-node tile, 4 waves x 32 nodes (2 m-blocks). No LDS.
__global__ __launch_bounds__(256) void out_kernel(
        const float* __restrict__ x, const unsigned* __restrict__ xpb,
        const int* __restrict__ batch, const unsigned* __restrict__ Wo,
        const float* __restrict__ agg_proj, float* __restrict__ out) {
    const int t = threadIdx.x;
    const int w = t >> 6, l = t & 63, lr = l & 15, lk = l >> 4;
    const int nb = blockIdx.x * 128 + w * 32;
    int rowc[2];
#pragma unroll
    for (int m = 0; m < 2; ++m) rowc[m] = min(nb + m * 16 + lr, N_NODES - 1);

    const f32x4 z4 = {0.f, 0.f, 0.f, 0.f};
    f32x4 acc[2][4];
#pragma unroll
    for (int m = 0; m < 2; ++m)
#pragma unroll
        for (int nr = 0; nr < 4; ++nr) acc[m][nr] = z4;

#pragma unroll
    for (int ks = 0; ks < 8; ++ks) {
        bf16x8 af[2];
        if (ks < 4) {
#pragma unroll
            for (int m = 0; m < 2; ++m) {
                const float4* xp4 = (const float4*)(x + (size_t)rowc[m] * 128 + ks * 32 + lk * 8);
                af[m] = pack8(xp4[0], xp4[1]);
            }
        } else {
#pragma unroll
            for (int m = 0; m < 2; ++m)
                af[m] = *(const bf16x8*)&xpb[(size_t)rowc[m] * 64 + (ks - 4) * 16 + lk * 4];
        }
#pragma unroll
        for (int nr = 0; nr < 4; ++nr) {
            bf16x8 bfrag = *(const bf16x8*)&Wo[(nr * 16 + lr) * 128 + ks * 16 + lk * 4];
#pragma unroll
            for (int m = 0; m < 2; ++m)
                acc[m][nr] = __builtin_amdgcn_mfma_f32_16x16x32_bf16(af[m], bfrag, acc[m][nr], 0, 0, 0);
        }
    }
#pragma unroll
    for (int m = 0; m < 2; ++m)
#pragma unroll
        for (int r = 0; r < 4; ++r) {
            int n = nb + m * 16 + lk * 4 + r;
            if (n < N_NODES) {
                int bs = batch[n];
                const float* ap = agg_proj + (size_t)bs * 64;
#pragma unroll
                for (int nr = 0; nr < 4; ++nr) {
                    int f = nr * 16 + lr;
                    out[(size_t)n * 64 + f] =
                        fmaxf(((const float*)&acc[m][nr])[r] + ap[f], 0.f);
                }
            }
        }
}

extern "C" void kernel_launch(void* const* d_in, const int* in_sizes, int n_in,
                              void* d_out, int out_size, void* d_ws, size_t ws_size,
                              hipStream_t stream) {
    const float* x     = (const float*)d_in[0];
    const int*   batch = (const int*)d_in[1];
    const float* W_in  = (const float*)d_in[3];
    const float* b_in  = (const float*)d_in[4];
    const float* W_a   = (const float*)d_in[5];
    const float* b_a   = (const float*)d_in[6];
    const float* W_out = (const float*)d_in[7];
    const float* b_out = (const float*)d_in[8];
    float* out = (float*)d_out;

    unsigned* xpb = (unsigned*)d_ws;                       // N*64 u32 (bf16 xp)
    float* score  = (float*)(xpb + (size_t)N_NODES * 64);  // N*8 f32
    float* agg_proj = score + (size_t)N_NODES * 8;         // 512*64 f32
    int* seg_start = (int*)(agg_proj + B_SEGS * D_OUTPUT); // 513 ints
    unsigned* Wb = (unsigned*)(seg_start + 520);           // 128*64
    unsigned* Wa = Wb + 128 * 64;                          // 16*64
    unsigned* Wo = Wa + 16 * 64;                           // 64*128

    seg_bounds_kernel<<<1, 1024, 0, stream>>>(batch, N_NODES, seg_start);
    wconv_kernel<<<1, 256, 0, stream>>>(W_in, W_a, W_out, Wb, Wa, Wo);
    fused_in_kernel<<<(N_NODES + 63) / 64, 256, 0, stream>>>(
        x, b_in, b_a, Wb, Wa, xpb, score);
    seg_kernel<<<B_SEGS, 256, 0, stream>>>(xpb, score, seg_start, W_out, b_out, agg_proj);
    out_kernel<<<(N_NODES + 127) / 128, 256, 0, stream>>>(
        x, xpb, batch, Wo, agg_proj, out);
}